// Round 2
// baseline (1694.163 us; speedup 1.0000x reference)
//
#include <hip/hip_runtime.h>
#include <hip/hip_bf16.h>
#include <cmath>

// TransformerBlock: N=50000, C=256, H=8, HD=32, M=800000 edges, HID=1024.
// Round 2: correct baseline, shrunk workspace (~126 MiB; round-1 needed 311MB
// and crashed => suspected ws overflow page fault).
//   LN1 -> QKV gemm (bf16 out, q scaled) -> edge bucket (hist/scan/scatter) ->
//   per-node 2-pass softmax attention (bf16 gathers, fp32 acc) ->
//   proj gemm (+skip -> d_out) -> LN2 -> 4x chunked [fc1+gelu ; fc2+=d_out]
// ws layout: B1 fp32 N*256 (51.2MB) | QKVh bf16 N*768 (76.8MB, reused as
//            fp32 N*256 MLP chunk buf) | int meta 3.8MB.

#define N_NODES 50000
#define C_DIM 256
#define M_EDGES 800000
#define ATT_SCALE 0.17677669529663687f /* 32^-0.5 */
#define LN_EPS 1e-5f

typedef unsigned int uint_t;
typedef unsigned short ushort_t;

__device__ inline ushort_t f2bf(float f) {
  uint_t u = __float_as_uint(f);
  return (ushort_t)((u + 0x7FFFu + ((u >> 16) & 1u)) >> 16);  // RNE
}
__device__ inline float bf_even(uint_t u) { return __uint_as_float(u << 16); }
__device__ inline float bf_odd(uint_t u) { return __uint_as_float(u & 0xFFFF0000u); }

// ---------------------------------------------------------------- LayerNorm
__global__ __launch_bounds__(256) void ln_kernel(const float* __restrict__ x,
    const float* __restrict__ g, const float* __restrict__ b,
    float* __restrict__ y)
{
  __shared__ float red[8];
  const int n = blockIdx.x;
  const int t = threadIdx.x;
  float v = x[(size_t)n * C_DIM + t];
  float s = v, s2 = v * v;
#pragma unroll
  for (int m = 1; m < 64; m <<= 1) {
    s += __shfl_xor(s, m);
    s2 += __shfl_xor(s2, m);
  }
  const int wave = t >> 6;
  if ((t & 63) == 0) { red[wave] = s; red[4 + wave] = s2; }
  __syncthreads();
  s = red[0] + red[1] + red[2] + red[3];
  s2 = red[4] + red[5] + red[6] + red[7];
  const float mean = s * (1.0f / 256.0f);
  const float var = fmaxf(s2 * (1.0f / 256.0f) - mean * mean, 0.0f);
  const float r = rsqrtf(var + LN_EPS);
  y[(size_t)n * C_DIM + t] = (v - mean) * r * g[t] + b[t];
}

// ---------------------------------------------------------------- GEMM
// Out[n][j] = sum_k A[n][k]*W[j][k] (+bias) (+epilogue)
// EPI 0: (acc+bias); cols<256 *= ATT_SCALE; store bf16 (qkv)
// EPI 1: acc+bias+extra  -> fp32 (proj+skip, fc2 chunk0 +fc2_b+F2)
// EPI 2: gelu(acc+bias)  -> fp32 (fc1 chunks)
// EPI 3: acc+extra       -> fp32 (fc2 chunks 1..3, accumulate into d_out)
// A: fp32, row stride = Kdim. W: fp32, row stride = Wld.
template <int EPI>
__global__ __launch_bounds__(256) void gemm_kernel(const float* __restrict__ A,
    const float* __restrict__ W, const float* __restrict__ bias,
    const float* __restrict__ extra, void* __restrict__ OutV,
    int Kdim, int Jdim, int Wld, int OutLd)
{
  __shared__ float As[32][68];
  __shared__ float Ws[32][68];
  const int t = threadIdx.x;
  const int rowbase = blockIdx.y * 64;
  const int colbase = blockIdx.x * 64;
  const int tx = t & 15;
  const int ty = t >> 4;
  const int r0 = t >> 3;        // 0..31
  const int c0 = (t & 7) << 2;  // 0..28 step 4
  float acc[4][4] = {{0.f}};

  for (int k0 = 0; k0 < Kdim; k0 += 32) {
#pragma unroll
    for (int half = 0; half < 2; ++half) {
      const int r = r0 + half * 32;
      const int grow = rowbase + r;
      float4 av = make_float4(0.f, 0.f, 0.f, 0.f);
      if (grow < N_NODES)
        av = *(const float4*)(A + (size_t)grow * Kdim + k0 + c0);
      As[c0 + 0][r] = av.x; As[c0 + 1][r] = av.y;
      As[c0 + 2][r] = av.z; As[c0 + 3][r] = av.w;
      const int gcol = colbase + r;  // Jdim multiple of 64
      const float4 wv = *(const float4*)(W + (size_t)gcol * Wld + k0 + c0);
      Ws[c0 + 0][r] = wv.x; Ws[c0 + 1][r] = wv.y;
      Ws[c0 + 2][r] = wv.z; Ws[c0 + 3][r] = wv.w;
    }
    __syncthreads();
#pragma unroll
    for (int kk = 0; kk < 32; ++kk) {
      const float4 a4 = *(const float4*)&As[kk][ty << 2];
      const float4 w4 = *(const float4*)&Ws[kk][tx << 2];
      const float av[4] = {a4.x, a4.y, a4.z, a4.w};
      const float wv[4] = {w4.x, w4.y, w4.z, w4.w};
#pragma unroll
      for (int i = 0; i < 4; ++i)
#pragma unroll
        for (int j = 0; j < 4; ++j)
          acc[i][j] = fmaf(av[i], wv[j], acc[i][j]);
    }
    __syncthreads();
  }

  const int gcol0 = colbase + (tx << 2);
  float b4[4] = {0.f, 0.f, 0.f, 0.f};
  if (EPI != 3) {
    b4[0] = bias[gcol0]; b4[1] = bias[gcol0 + 1];
    b4[2] = bias[gcol0 + 2]; b4[3] = bias[gcol0 + 3];
  }
#pragma unroll
  for (int i = 0; i < 4; ++i) {
    const int grow = rowbase + (ty << 2) + i;
    if (grow >= N_NODES) break;
    float o[4];
#pragma unroll
    for (int j = 0; j < 4; ++j) {
      float v = acc[i][j] + b4[j];
      if (EPI == 0) {
        if (gcol0 + j < 256) v *= ATT_SCALE;
      } else if (EPI == 1) {
        v += extra[(size_t)grow * OutLd + gcol0 + j];
      } else if (EPI == 2) {
        v = 0.5f * v * (1.0f + erff(v * 0.70710678118654752f));
      } else if (EPI == 3) {
        v += extra[(size_t)grow * OutLd + gcol0 + j];
      }
      o[j] = v;
    }
    if (EPI == 0) {
      ushort4 st;
      st.x = f2bf(o[0]); st.y = f2bf(o[1]);
      st.z = f2bf(o[2]); st.w = f2bf(o[3]);
      *(ushort4*)((ushort_t*)OutV + (size_t)grow * OutLd + gcol0) = st;
    } else {
      *(float4*)((float*)OutV + (size_t)grow * OutLd + gcol0) = *(float4*)o;
    }
  }
}

// ---------------------------------------------------------------- edge bucket
__global__ void hist_kernel(const int* __restrict__ idx0, int* __restrict__ counts)
{
  const int m = blockIdx.x * 256 + threadIdx.x;
  if (m < M_EDGES) atomicAdd(&counts[idx0[m]], 1);
}

__global__ __launch_bounds__(1024) void scan_kernel(const int* __restrict__ counts,
                                                    int* __restrict__ offsets)
{
  __shared__ int tmp[1024];
  __shared__ int carry_sh;
  const int t = threadIdx.x;
  if (t == 0) carry_sh = 0;
  __syncthreads();
  for (int base = 0; base < N_NODES; base += 1024) {
    const int i = base + t;
    const int v = (i < N_NODES) ? counts[i] : 0;
    int x = v;
    tmp[t] = x;
    __syncthreads();
    for (int off = 1; off < 1024; off <<= 1) {
      const int a = (t >= off) ? tmp[t - off] : 0;
      __syncthreads();
      x += a;
      tmp[t] = x;
      __syncthreads();
    }
    const int carry = carry_sh;
    if (i < N_NODES) offsets[i] = carry + x - v;  // exclusive
    const int tot = tmp[1023];
    __syncthreads();
    if (t == 0) carry_sh = carry + tot;
    __syncthreads();
  }
  if (t == 0) offsets[N_NODES] = M_EDGES;
}

__global__ void scatter_kernel(const int* __restrict__ idx0,
    const int* __restrict__ idx1, const int* __restrict__ offsets,
    int* __restrict__ cursor, int* __restrict__ srcs)
{
  const int m = blockIdx.x * 256 + threadIdx.x;
  if (m < M_EDGES) {
    const int n = idx0[m];
    const int p = offsets[n] + atomicAdd(&cursor[n], 1);
    srcs[p] = idx1[m];
  }
}

// ---------------------------------------------------------------- attention
// One wave per node; lane = slot(0..7) x head(0..7). QKV rows are bf16 (768
// per node: q 0..255, k 256..511, v 512..767). Two passes: max, exp/sum+V.
__global__ __launch_bounds__(256) void attn_kernel(
    const ushort_t* __restrict__ QKVh, const int* __restrict__ offsets,
    const int* __restrict__ srcs, float* __restrict__ AO)
{
  const int node = blockIdx.x * 4 + (threadIdx.x >> 6);
  if (node >= N_NODES) return;
  const int lane = threadIdx.x & 63;
  const int h = lane & 7;
  const int slot = lane >> 3;
  const int start = offsets[node];
  const int end = offsets[node + 1];

  float q[32];
  {
    const uint4* qr = (const uint4*)(QKVh + (size_t)node * 768 + h * 32);
#pragma unroll
    for (int i = 0; i < 4; ++i) {
      const uint4 u = qr[i];
      q[i * 8 + 0] = bf_even(u.x); q[i * 8 + 1] = bf_odd(u.x);
      q[i * 8 + 2] = bf_even(u.y); q[i * 8 + 3] = bf_odd(u.y);
      q[i * 8 + 4] = bf_even(u.z); q[i * 8 + 5] = bf_odd(u.z);
      q[i * 8 + 6] = bf_even(u.w); q[i * 8 + 7] = bf_odd(u.w);
    }
  }

  float mloc = -3.0e38f;
  for (int e = start + slot; e < end; e += 8) {
    const uint4* kr = (const uint4*)(QKVh + (size_t)srcs[e] * 768 + 256 + h * 32);
    float d = 0.f;
#pragma unroll
    for (int i = 0; i < 4; ++i) {
      const uint4 u = kr[i];
      d += q[i * 8 + 0] * bf_even(u.x) + q[i * 8 + 1] * bf_odd(u.x);
      d += q[i * 8 + 2] * bf_even(u.y) + q[i * 8 + 3] * bf_odd(u.y);
      d += q[i * 8 + 4] * bf_even(u.z) + q[i * 8 + 5] * bf_odd(u.z);
      d += q[i * 8 + 6] * bf_even(u.w) + q[i * 8 + 7] * bf_odd(u.w);
    }
    mloc = fmaxf(mloc, d);
  }
  mloc = fmaxf(mloc, __shfl_xor(mloc, 8));
  mloc = fmaxf(mloc, __shfl_xor(mloc, 16));
  mloc = fmaxf(mloc, __shfl_xor(mloc, 32));

  float ssum = 0.f;
  float o[32];
#pragma unroll
  for (int d = 0; d < 32; ++d) o[d] = 0.f;

  for (int e = start + slot; e < end; e += 8) {
    const int sidx = srcs[e];
    const uint4* kr = (const uint4*)(QKVh + (size_t)sidx * 768 + 256 + h * 32);
    float d = 0.f;
#pragma unroll
    for (int i = 0; i < 4; ++i) {
      const uint4 u = kr[i];
      d += q[i * 8 + 0] * bf_even(u.x) + q[i * 8 + 1] * bf_odd(u.x);
      d += q[i * 8 + 2] * bf_even(u.y) + q[i * 8 + 3] * bf_odd(u.y);
      d += q[i * 8 + 4] * bf_even(u.z) + q[i * 8 + 5] * bf_odd(u.z);
      d += q[i * 8 + 6] * bf_even(u.w) + q[i * 8 + 7] * bf_odd(u.w);
    }
    const float w = expf(d - mloc);
    ssum += w;
    const uint4* vr = (const uint4*)(QKVh + (size_t)sidx * 768 + 512 + h * 32);
#pragma unroll
    for (int i = 0; i < 4; ++i) {
      const uint4 u = vr[i];
      o[i * 8 + 0] += w * bf_even(u.x); o[i * 8 + 1] += w * bf_odd(u.x);
      o[i * 8 + 2] += w * bf_even(u.y); o[i * 8 + 3] += w * bf_odd(u.y);
      o[i * 8 + 4] += w * bf_even(u.z); o[i * 8 + 5] += w * bf_odd(u.z);
      o[i * 8 + 6] += w * bf_even(u.w); o[i * 8 + 7] += w * bf_odd(u.w);
    }
  }
  ssum += __shfl_xor(ssum, 8);
  ssum += __shfl_xor(ssum, 16);
  ssum += __shfl_xor(ssum, 32);

  // reduce-scatter o[32] across 8 slots (static reg indices)
  {
    const bool up = (slot & 4) != 0;
#pragma unroll
    for (int i = 0; i < 16; ++i) {
      const float send = up ? o[i] : o[i + 16];
      const float recv = __shfl_xor(send, 32);
      o[i] = (up ? o[i + 16] : o[i]) + recv;
    }
  }
  {
    const bool up = (slot & 2) != 0;
#pragma unroll
    for (int i = 0; i < 8; ++i) {
      const float send = up ? o[i] : o[i + 8];
      const float recv = __shfl_xor(send, 16);
      o[i] = (up ? o[i + 8] : o[i]) + recv;
    }
  }
  {
    const bool up = (slot & 1) != 0;
#pragma unroll
    for (int i = 0; i < 4; ++i) {
      const float send = up ? o[i] : o[i + 4];
      const float recv = __shfl_xor(send, 8);
      o[i] = (up ? o[i + 4] : o[i]) + recv;
    }
  }
  const int dbase = ((slot & 4) ? 16 : 0) + ((slot & 2) ? 8 : 0) +
                    ((slot & 1) ? 4 : 0);
  const float inv = (end > start) ? 1.0f / ssum : 0.0f;
  const float4 res = make_float4(o[0] * inv, o[1] * inv, o[2] * inv, o[3] * inv);
  *(float4*)(AO + (size_t)node * 256 + h * 32 + dbase) = res;
}

// ---------------------------------------------------------------- launch
extern "C" void kernel_launch(void* const* d_in, const int* in_sizes, int n_in,
                              void* d_out, int out_size, void* d_ws,
                              size_t ws_size, hipStream_t stream)
{
  const float* feats  = (const float*)d_in[0];
  const int*   edge   = (const int*)d_in[2];
  const float* ln1_g  = (const float*)d_in[3];
  const float* ln1_b  = (const float*)d_in[4];
  const float* qkv_w  = (const float*)d_in[5];
  const float* qkv_b  = (const float*)d_in[6];
  const float* proj_w = (const float*)d_in[7];
  const float* proj_b = (const float*)d_in[8];
  const float* ln2_g  = (const float*)d_in[9];
  const float* ln2_b  = (const float*)d_in[10];
  const float* fc1_w  = (const float*)d_in[11];
  const float* fc1_b  = (const float*)d_in[12];
  const float* fc2_w  = (const float*)d_in[13];
  const float* fc2_b  = (const float*)d_in[14];
  float* out = (float*)d_out;

  // ws layout
  float*    B1   = (float*)d_ws;                          // N*256 fp32
  ushort_t* QKVh = (ushort_t*)(B1 + (size_t)N_NODES * 256);  // N*768 bf16
  float*    Hc   = (float*)QKVh;  // overlay: N*256 fp32 (QKV dead by then)
  int* counts  = (int*)(QKVh + (size_t)N_NODES * 768);
  int* cursor  = counts + N_NODES;
  int* offsets = cursor + N_NODES;
  int* srcs    = offsets + N_NODES + 1;
  const size_t required = (size_t)(srcs + M_EDGES) - (size_t)d_ws;
  if (ws_size < required) {  // diagnostic fallback: fail absmax, don't fault
    hipMemsetAsync(d_out, 0, (size_t)out_size * sizeof(float), stream);
    return;
  }
  const int* idx0 = edge;
  const int* idx1 = edge + M_EDGES;
  const int rowTiles = (N_NODES + 63) / 64;

  hipMemsetAsync(counts, 0, 2 * N_NODES * sizeof(int), stream);
  ln_kernel<<<N_NODES, 256, 0, stream>>>(feats, ln1_g, ln1_b, B1);
  gemm_kernel<0><<<dim3(768 / 64, rowTiles), 256, 0, stream>>>(
      B1, qkv_w, qkv_b, nullptr, QKVh, 256, 768, 256, 768);
  hist_kernel<<<(M_EDGES + 255) / 256, 256, 0, stream>>>(idx0, counts);
  scan_kernel<<<1, 1024, 0, stream>>>(counts, offsets);
  scatter_kernel<<<(M_EDGES + 255) / 256, 256, 0, stream>>>(idx0, idx1, offsets,
                                                            cursor, srcs);
  attn_kernel<<<N_NODES / 4, 256, 0, stream>>>(QKVh, offsets, srcs, B1);
  gemm_kernel<1><<<dim3(256 / 64, rowTiles), 256, 0, stream>>>(
      B1, proj_w, proj_b, feats, out, 256, 256, 256, 256);
  ln_kernel<<<N_NODES, 256, 0, stream>>>(out, ln2_g, ln2_b, B1);
  for (int c = 0; c < 4; ++c) {
    gemm_kernel<2><<<dim3(256 / 64, rowTiles), 256, 0, stream>>>(
        B1, fc1_w + (size_t)c * 256 * 256, fc1_b + c * 256, nullptr, Hc,
        256, 256, 256, 256);
    if (c == 0)
      gemm_kernel<1><<<dim3(256 / 64, rowTiles), 256, 0, stream>>>(
          Hc, fc2_w + c * 256, fc2_b, out, out, 256, 256, 1024, 256);
    else
      gemm_kernel<3><<<dim3(256 / 64, rowTiles), 256, 0, stream>>>(
          Hc, fc2_w + c * 256, nullptr, out, out, 256, 256, 1024, 256);
  }
}

// Round 3
// 768.232 us; speedup vs baseline: 2.2053x; 2.2053x over previous
//
#include <hip/hip_runtime.h>
#include <hip/hip_bf16.h>
#include <cmath>

// TransformerBlock: N=50000, C=256, H=8, HD=32, M=800000 edges, HID=1024.
// Round 3: bf16 MFMA GEMMs (m97-style: 128x128 tile, BK=32, global_load_lds
// width 16, swizzled LDS, 16x16x32 bf16 MFMA). bf16 activations everywhere,
// fp32 accumulate; residual chain kept fp32 in d_out.
//   LN1(bf16 out) -> QKV mfma-gemm (bf16, q scaled) -> hist/scan/scatter ->
//   attention (bf16 gathers) -> proj mfma-gemm (+feats -> d_out fp32) ->
//   LN2 -> fc1 mfma-gemm (gelu, bf16 H) -> fc2 mfma-gemm (+d_out -> d_out)
// ws: Xb 25.6MB | QKVh 76.8MB | AOb 25.6MB (QKVh+AOb reused as H 102.4MB)
//     | wb 1.6MB | int meta 3.8MB  => ~133.4MB (round-2 budget held).

#define N_NODES 50000
#define C_DIM 256
#define M_EDGES 800000
#define ATT_SCALE 0.17677669529663687f /* 32^-0.5 */
#define LN_EPS 1e-5f

typedef unsigned int uint_t;
typedef unsigned short ushort_t;
typedef short short8 __attribute__((ext_vector_type(8)));
typedef float floatx4 __attribute__((ext_vector_type(4)));

__device__ __forceinline__ ushort_t f2bf(float f) {
  uint_t u = __float_as_uint(f);
  return (ushort_t)((u + 0x7FFFu + ((u >> 16) & 1u)) >> 16);  // RNE
}
__device__ __forceinline__ float bf_even(uint_t u) { return __uint_as_float(u << 16); }
__device__ __forceinline__ float bf_odd(uint_t u) { return __uint_as_float(u & 0xFFFF0000u); }

__device__ __forceinline__ void gload16(const void* g, void* l) {
  __builtin_amdgcn_global_load_lds(
      (const __attribute__((address_space(1))) void*)g,
      (__attribute__((address_space(3))) void*)l, 16, 0, 0);
}

// ---------------------------------------------------------------- LayerNorm
// reads fp32 x, writes bf16 y
__global__ __launch_bounds__(256) void ln_kernel(const float* __restrict__ x,
    const float* __restrict__ g, const float* __restrict__ b,
    ushort_t* __restrict__ y)
{
  __shared__ float red[8];
  const int n = blockIdx.x;
  const int t = threadIdx.x;
  float v = x[(size_t)n * C_DIM + t];
  float s = v, s2 = v * v;
#pragma unroll
  for (int m = 1; m < 64; m <<= 1) {
    s += __shfl_xor(s, m);
    s2 += __shfl_xor(s2, m);
  }
  const int wave = t >> 6;
  if ((t & 63) == 0) { red[wave] = s; red[4 + wave] = s2; }
  __syncthreads();
  s = red[0] + red[1] + red[2] + red[3];
  s2 = red[4] + red[5] + red[6] + red[7];
  const float mean = s * (1.0f / 256.0f);
  const float var = fmaxf(s2 * (1.0f / 256.0f) - mean * mean, 0.0f);
  const float r = rsqrtf(var + LN_EPS);
  y[(size_t)n * C_DIM + t] = f2bf((v - mean) * r * g[t] + b[t]);
}

// ---------------------------------------------------------------- fp32->bf16
__global__ void cvt_kernel(const float* __restrict__ src,
                           ushort_t* __restrict__ dst, int n)
{
  const int i = blockIdx.x * 256 + threadIdx.x;
  if (i < n) dst[i] = f2bf(src[i]);
}

// ---------------------------------------------------------------- MFMA GEMM
// Out[n][j] = sum_k A[n][k]*W[j][k] + bias[j] (+ epilogue).
// A: bf16, ld=Kdim. W: bf16, ld=Kdim. Jdim multiple of 128; Kdim mult of 32.
// EPI 0: cols<256 *= ATT_SCALE; store bf16 (qkv)
// EPI 1: + extra[n][j]; store fp32 (proj+skip, fc2+skip)
// EPI 2: exact gelu; store bf16 (fc1)
// 128x128 tile, BK=32, 4 waves; wave -> 64x64 quadrant as 4x4 16x16x32 MFMAs.
// LDS chunk swizzle: chunk (r, kc) stored at kc_lds = kc ^ ((r>>2)&3) so
// ds_read_b128 fragment loads are <=2-way bank aliased (free).
template <int EPI>
__global__ __launch_bounds__(256, 2) void mfma_gemm(
    const ushort_t* __restrict__ A, const ushort_t* __restrict__ W,
    const float* __restrict__ bias, const float* __restrict__ extra,
    void* __restrict__ OutV, int Kdim, int Jdim)
{
  __shared__ __align__(16) ushort_t As[128 * 32];
  __shared__ __align__(16) ushort_t Bs[128 * 32];
  const int t = threadIdx.x;
  const int lane = t & 63;
  const int w = t >> 6;
  const int wm = w & 1;
  const int wn = w >> 1;
  const int rowbase = blockIdx.y * 128;
  const int colbase = blockIdx.x * 128;

  floatx4 acc[4][4] = {};

  // Precompute staging descriptors: 2 issues x (A,B). Chunk cidx covers
  // (row r = cidx>>2, LDS k-chunk = cidx&3); global k-chunk is swizzled.
  int rA[2], kcg[2];
#pragma unroll
  for (int h = 0; h < 2; ++h) {
    const int cidx = h * 256 + w * 64 + lane;
    const int r = cidx >> 2;
    rA[h] = r;
    kcg[h] = (cidx & 3) ^ ((r >> 2) & 3);
  }

  const int rl = lane & 15;
  const int qd = lane >> 4;       // 0..3
  const int sw = (rl >> 2) & 3;   // fragment-read swizzle

  for (int k0 = 0; k0 < Kdim; k0 += 32) {
#pragma unroll
    for (int h = 0; h < 2; ++h) {
      const int r = rA[h];
      int grow = rowbase + r;
      if (grow > N_NODES - 1) grow = N_NODES - 1;  // clamp tail rows
      const int gcol = colbase + r;                // Jdim multiple of 128
      const size_t ka = (size_t)grow * Kdim + k0 + kcg[h] * 8;
      const size_t kb = (size_t)gcol * Kdim + k0 + kcg[h] * 8;
      ushort_t* lbase_a = As + (size_t)(h * 256 + w * 64) * 8;
      ushort_t* lbase_b = Bs + (size_t)(h * 256 + w * 64) * 8;
      gload16(A + ka, lbase_a);
      gload16(W + kb, lbase_b);
    }
    __syncthreads();

    short8 af[4], bf[4];
#pragma unroll
    for (int tm = 0; tm < 4; ++tm) {
      const int ra = wm * 64 + tm * 16 + rl;
      af[tm] = *(const short8*)(As + ra * 32 + ((qd ^ sw) << 3));
    }
#pragma unroll
    for (int tn = 0; tn < 4; ++tn) {
      const int rb = wn * 64 + tn * 16 + rl;
      bf[tn] = *(const short8*)(Bs + rb * 32 + ((qd ^ sw) << 3));
    }
#pragma unroll
    for (int tm = 0; tm < 4; ++tm)
#pragma unroll
      for (int tn = 0; tn < 4; ++tn)
        acc[tm][tn] = __builtin_amdgcn_mfma_f32_16x16x32_bf16(
            af[tm], bf[tn], acc[tm][tn], 0, 0, 0);
    __syncthreads();
  }

  // Epilogue. C/D layout: col = lane&15, row = (lane>>4)*4 + reg.
#pragma unroll
  for (int tn = 0; tn < 4; ++tn) {
    const int col = colbase + wn * 64 + tn * 16 + rl;
    const float bv = bias[col];
#pragma unroll
    for (int tm = 0; tm < 4; ++tm) {
      const int row0 = rowbase + wm * 64 + tm * 16 + qd * 4;
#pragma unroll
      for (int r = 0; r < 4; ++r) {
        const int row = row0 + r;
        if (row >= N_NODES) continue;
        float v = acc[tm][tn][r] + bv;
        if (EPI == 0) {
          if (col < 256) v *= ATT_SCALE;
          ((ushort_t*)OutV)[(size_t)row * Jdim + col] = f2bf(v);
        } else if (EPI == 1) {
          v += extra[(size_t)row * Jdim + col];
          ((float*)OutV)[(size_t)row * Jdim + col] = v;
        } else {
          v = 0.5f * v * (1.0f + erff(v * 0.70710678118654752f));
          ((ushort_t*)OutV)[(size_t)row * Jdim + col] = f2bf(v);
        }
      }
    }
  }
}

// ---------------------------------------------------------------- edge bucket
__global__ void hist_kernel(const int* __restrict__ idx0, int* __restrict__ counts)
{
  const int m = blockIdx.x * 256 + threadIdx.x;
  if (m < M_EDGES) atomicAdd(&counts[idx0[m]], 1);
}

__global__ __launch_bounds__(1024) void scan_kernel(const int* __restrict__ counts,
                                                    int* __restrict__ offsets)
{
  __shared__ int tmp[1024];
  __shared__ int carry_sh;
  const int t = threadIdx.x;
  if (t == 0) carry_sh = 0;
  __syncthreads();
  for (int base = 0; base < N_NODES; base += 1024) {
    const int i = base + t;
    const int v = (i < N_NODES) ? counts[i] : 0;
    int x = v;
    tmp[t] = x;
    __syncthreads();
    for (int off = 1; off < 1024; off <<= 1) {
      const int a = (t >= off) ? tmp[t - off] : 0;
      __syncthreads();
      x += a;
      tmp[t] = x;
      __syncthreads();
    }
    const int carry = carry_sh;
    if (i < N_NODES) offsets[i] = carry + x - v;  // exclusive
    const int tot = tmp[1023];
    __syncthreads();
    if (t == 0) carry_sh = carry + tot;
    __syncthreads();
  }
  if (t == 0) offsets[N_NODES] = M_EDGES;
}

__global__ void scatter_kernel(const int* __restrict__ idx0,
    const int* __restrict__ idx1, const int* __restrict__ offsets,
    int* __restrict__ cursor, int* __restrict__ srcs)
{
  const int m = blockIdx.x * 256 + threadIdx.x;
  if (m < M_EDGES) {
    const int n = idx0[m];
    const int p = offsets[n] + atomicAdd(&cursor[n], 1);
    srcs[p] = idx1[m];
  }
}

// ---------------------------------------------------------------- attention
// One wave per node; lane = slot(0..7) x head(0..7). QKV bf16 (768/node:
// q 0..255, k 256..511, v 512..767). Two passes: max, then exp/sum + V.
__global__ __launch_bounds__(256) void attn_kernel(
    const ushort_t* __restrict__ QKVh, const int* __restrict__ offsets,
    const int* __restrict__ srcs, ushort_t* __restrict__ AO)
{
  const int node = blockIdx.x * 4 + (threadIdx.x >> 6);
  if (node >= N_NODES) return;
  const int lane = threadIdx.x & 63;
  const int h = lane & 7;
  const int slot = lane >> 3;
  const int start = offsets[node];
  const int end = offsets[node + 1];

  float q[32];
  {
    const uint4* qr = (const uint4*)(QKVh + (size_t)node * 768 + h * 32);
#pragma unroll
    for (int i = 0; i < 4; ++i) {
      const uint4 u = qr[i];
      q[i * 8 + 0] = bf_even(u.x); q[i * 8 + 1] = bf_odd(u.x);
      q[i * 8 + 2] = bf_even(u.y); q[i * 8 + 3] = bf_odd(u.y);
      q[i * 8 + 4] = bf_even(u.z); q[i * 8 + 5] = bf_odd(u.z);
      q[i * 8 + 6] = bf_even(u.w); q[i * 8 + 7] = bf_odd(u.w);
    }
  }

  float mloc = -3.0e38f;
  for (int e = start + slot; e < end; e += 8) {
    const uint4* kr = (const uint4*)(QKVh + (size_t)srcs[e] * 768 + 256 + h * 32);
    float d = 0.f;
#pragma unroll
    for (int i = 0; i < 4; ++i) {
      const uint4 u = kr[i];
      d += q[i * 8 + 0] * bf_even(u.x) + q[i * 8 + 1] * bf_odd(u.x);
      d += q[i * 8 + 2] * bf_even(u.y) + q[i * 8 + 3] * bf_odd(u.y);
      d += q[i * 8 + 4] * bf_even(u.z) + q[i * 8 + 5] * bf_odd(u.z);
      d += q[i * 8 + 6] * bf_even(u.w) + q[i * 8 + 7] * bf_odd(u.w);
    }
    mloc = fmaxf(mloc, d);
  }
  mloc = fmaxf(mloc, __shfl_xor(mloc, 8));
  mloc = fmaxf(mloc, __shfl_xor(mloc, 16));
  mloc = fmaxf(mloc, __shfl_xor(mloc, 32));

  float ssum = 0.f;
  float o[32];
#pragma unroll
  for (int d = 0; d < 32; ++d) o[d] = 0.f;

  for (int e = start + slot; e < end; e += 8) {
    const int sidx = srcs[e];
    const uint4* kr = (const uint4*)(QKVh + (size_t)sidx * 768 + 256 + h * 32);
    float d = 0.f;
#pragma unroll
    for (int i = 0; i < 4; ++i) {
      const uint4 u = kr[i];
      d += q[i * 8 + 0] * bf_even(u.x) + q[i * 8 + 1] * bf_odd(u.x);
      d += q[i * 8 + 2] * bf_even(u.y) + q[i * 8 + 3] * bf_odd(u.y);
      d += q[i * 8 + 4] * bf_even(u.z) + q[i * 8 + 5] * bf_odd(u.z);
      d += q[i * 8 + 6] * bf_even(u.w) + q[i * 8 + 7] * bf_odd(u.w);
    }
    const float wgt = expf(d - mloc);
    ssum += wgt;
    const uint4* vr = (const uint4*)(QKVh + (size_t)sidx * 768 + 512 + h * 32);
#pragma unroll
    for (int i = 0; i < 4; ++i) {
      const uint4 u = vr[i];
      o[i * 8 + 0] += wgt * bf_even(u.x); o[i * 8 + 1] += wgt * bf_odd(u.x);
      o[i * 8 + 2] += wgt * bf_even(u.y); o[i * 8 + 3] += wgt * bf_odd(u.y);
      o[i * 8 + 4] += wgt * bf_even(u.z); o[i * 8 + 5] += wgt * bf_odd(u.z);
      o[i * 8 + 6] += wgt * bf_even(u.w); o[i * 8 + 7] += wgt * bf_odd(u.w);
    }
  }
  ssum += __shfl_xor(ssum, 8);
  ssum += __shfl_xor(ssum, 16);
  ssum += __shfl_xor(ssum, 32);

  // reduce-scatter o[32] across 8 slots (static reg indices only)
  {
    const bool up = (slot & 4) != 0;
#pragma unroll
    for (int i = 0; i < 16; ++i) {
      const float send = up ? o[i] : o[i + 16];
      const float recv = __shfl_xor(send, 32);
      o[i] = (up ? o[i + 16] : o[i]) + recv;
    }
  }
  {
    const bool up = (slot & 2) != 0;
#pragma unroll
    for (int i = 0; i < 8; ++i) {
      const float send = up ? o[i] : o[i + 8];
      const float recv = __shfl_xor(send, 16);
      o[i] = (up ? o[i + 8] : o[i]) + recv;
    }
  }
  {
    const bool up = (slot & 1) != 0;
#pragma unroll
    for (int i = 0; i < 4; ++i) {
      const float send = up ? o[i] : o[i + 4];
      const float recv = __shfl_xor(send, 8);
      o[i] = (up ? o[i + 4] : o[i]) + recv;
    }
  }
  const int dbase = ((slot & 4) ? 16 : 0) + ((slot & 2) ? 8 : 0) +
                    ((slot & 1) ? 4 : 0);
  const float inv = (end > start) ? 1.0f / ssum : 0.0f;
  ushort4 st;
  st.x = f2bf(o[0] * inv); st.y = f2bf(o[1] * inv);
  st.z = f2bf(o[2] * inv); st.w = f2bf(o[3] * inv);
  *(ushort4*)(AO + (size_t)node * 256 + h * 32 + dbase) = st;
}

// ---------------------------------------------------------------- launch
extern "C" void kernel_launch(void* const* d_in, const int* in_sizes, int n_in,
                              void* d_out, int out_size, void* d_ws,
                              size_t ws_size, hipStream_t stream)
{
  const float* feats  = (const float*)d_in[0];
  const int*   edge   = (const int*)d_in[2];
  const float* ln1_g  = (const float*)d_in[3];
  const float* ln1_b  = (const float*)d_in[4];
  const float* qkv_w  = (const float*)d_in[5];
  const float* qkv_b  = (const float*)d_in[6];
  const float* proj_w = (const float*)d_in[7];
  const float* proj_b = (const float*)d_in[8];
  const float* ln2_g  = (const float*)d_in[9];
  const float* ln2_b  = (const float*)d_in[10];
  const float* fc1_w  = (const float*)d_in[11];
  const float* fc1_b  = (const float*)d_in[12];
  const float* fc2_w  = (const float*)d_in[13];
  const float* fc2_b  = (const float*)d_in[14];
  float* out = (float*)d_out;

  // ws layout (QKVh+AOb contiguous -> reused as H bf16 N*1024)
  ushort_t* Xb   = (ushort_t*)d_ws;                       // N*256 bf16
  ushort_t* QKVh = Xb + (size_t)N_NODES * 256;            // N*768 bf16
  ushort_t* AOb  = QKVh + (size_t)N_NODES * 768;          // N*256 bf16
  ushort_t* Hb   = QKVh;                                  // N*1024 overlay
  ushort_t* qkv_wb  = AOb + (size_t)N_NODES * 256;        // 196608
  ushort_t* proj_wb = qkv_wb + 768 * 256;                 // 65536
  ushort_t* fc1_wb  = proj_wb + 256 * 256;                // 262144
  ushort_t* fc2_wb  = fc1_wb + 1024 * 256;                // 262144
  int* counts  = (int*)(fc2_wb + 256 * 1024);
  int* cursor  = counts + N_NODES;
  int* offsets = cursor + N_NODES;
  int* srcs    = offsets + N_NODES + 1;
  const size_t required = (size_t)((char*)(srcs + M_EDGES) - (char*)d_ws);
  if (ws_size < required) {  // diagnostic fallback: fail absmax, don't fault
    hipMemsetAsync(d_out, 0, (size_t)out_size * sizeof(float), stream);
    return;
  }
  const int* idx0 = edge;
  const int* idx1 = edge + M_EDGES;
  const int rowTiles = (N_NODES + 127) / 128;  // 391

  hipMemsetAsync(counts, 0, 2 * N_NODES * sizeof(int), stream);
  cvt_kernel<<<(768 * 256 + 255) / 256, 256, 0, stream>>>(qkv_w, qkv_wb, 768 * 256);
  cvt_kernel<<<(256 * 256 + 255) / 256, 256, 0, stream>>>(proj_w, proj_wb, 256 * 256);
  cvt_kernel<<<(1024 * 256 + 255) / 256, 256, 0, stream>>>(fc1_w, fc1_wb, 1024 * 256);
  cvt_kernel<<<(256 * 1024 + 255) / 256, 256, 0, stream>>>(fc2_w, fc2_wb, 256 * 1024);

  ln_kernel<<<N_NODES, 256, 0, stream>>>(feats, ln1_g, ln1_b, Xb);
  mfma_gemm<0><<<dim3(768 / 128, rowTiles), 256, 0, stream>>>(
      Xb, qkv_wb, qkv_b, nullptr, QKVh, 256, 768);
  hist_kernel<<<(M_EDGES + 255) / 256, 256, 0, stream>>>(idx0, counts);
  scan_kernel<<<1, 1024, 0, stream>>>(counts, offsets);
  scatter_kernel<<<(M_EDGES + 255) / 256, 256, 0, stream>>>(idx0, idx1, offsets,
                                                            cursor, srcs);
  attn_kernel<<<N_NODES / 4, 256, 0, stream>>>(QKVh, offsets, srcs, AOb);
  mfma_gemm<1><<<dim3(256 / 128, rowTiles), 256, 0, stream>>>(
      AOb, proj_wb, proj_b, feats, out, 256, 256);
  ln_kernel<<<N_NODES, 256, 0, stream>>>(out, ln2_g, ln2_b, Xb);
  mfma_gemm<2><<<dim3(1024 / 128, rowTiles), 256, 0, stream>>>(
      Xb, fc1_wb, fc1_b, nullptr, Hb, 256, 1024);
  mfma_gemm<1><<<dim3(256 / 128, rowTiles), 256, 0, stream>>>(
      Hb, fc2_wb, fc2_b, out, out, 1024, 256);
}

// Round 4
// 655.109 us; speedup vs baseline: 2.5861x; 1.1727x over previous
//
#include <hip/hip_runtime.h>
#include <hip/hip_bf16.h>
#include <cmath>

// TransformerBlock: N=50000, C=256, H=8, HD=32, M=800000 edges, HID=1024.
// Round 4: (1) one-pass online-softmax attention (K read once, was twice);
// (2) parallel 3-kernel scan (was single-block serial, ~40-80us);
// (3) MFMA GEMM BK=32 -> BK=64 (half the barrier drains, 32KB LDS);
// (4) fused weight-cvt kernel.
// ws: Xb 25.6MB | QKVh 76.8MB | AOb 25.6MB (QKVh+AOb reused as H 102.4MB)
//     | wb 1.6MB | int meta ~3.8MB => ~133.5MB.

#define N_NODES 50000
#define C_DIM 256
#define M_EDGES 800000
#define ATT_SCALE 0.17677669529663687f /* 32^-0.5 */
#define LN_EPS 1e-5f
#define LOG2E 1.4426950408889634f
#define NEG_BIG -3.0e38f

typedef unsigned int uint_t;
typedef unsigned short ushort_t;
typedef short short8 __attribute__((ext_vector_type(8)));
typedef float floatx4 __attribute__((ext_vector_type(4)));

__device__ __forceinline__ ushort_t f2bf(float f) {
  uint_t u = __float_as_uint(f);
  return (ushort_t)((u + 0x7FFFu + ((u >> 16) & 1u)) >> 16);  // RNE
}
__device__ __forceinline__ float bf_even(uint_t u) { return __uint_as_float(u << 16); }
__device__ __forceinline__ float bf_odd(uint_t u) { return __uint_as_float(u & 0xFFFF0000u); }

__device__ __forceinline__ void gload16(const void* g, void* l) {
  __builtin_amdgcn_global_load_lds(
      (const __attribute__((address_space(1))) void*)g,
      (__attribute__((address_space(3))) void*)l, 16, 0, 0);
}

// ---------------------------------------------------------------- LayerNorm
__global__ __launch_bounds__(256) void ln_kernel(const float* __restrict__ x,
    const float* __restrict__ g, const float* __restrict__ b,
    ushort_t* __restrict__ y)
{
  __shared__ float red[8];
  const int n = blockIdx.x;
  const int t = threadIdx.x;
  float v = x[(size_t)n * C_DIM + t];
  float s = v, s2 = v * v;
#pragma unroll
  for (int m = 1; m < 64; m <<= 1) {
    s += __shfl_xor(s, m);
    s2 += __shfl_xor(s2, m);
  }
  const int wave = t >> 6;
  if ((t & 63) == 0) { red[wave] = s; red[4 + wave] = s2; }
  __syncthreads();
  s = red[0] + red[1] + red[2] + red[3];
  s2 = red[4] + red[5] + red[6] + red[7];
  const float mean = s * (1.0f / 256.0f);
  const float var = fmaxf(s2 * (1.0f / 256.0f) - mean * mean, 0.0f);
  const float r = rsqrtf(var + LN_EPS);
  y[(size_t)n * C_DIM + t] = f2bf((v - mean) * r * g[t] + b[t]);
}

// ------------------------------------------------- fused fp32->bf16 weights
__global__ void cvt_kernel(const float* __restrict__ s0, const float* __restrict__ s1,
                           const float* __restrict__ s2, const float* __restrict__ s3,
                           ushort_t* __restrict__ dst)
{
  const int i = blockIdx.x * 256 + threadIdx.x;
  // segments: qkv_w 196608 | proj_w 65536 | fc1_w 262144 | fc2_w 262144
  float v;
  if (i < 196608) v = s0[i];
  else if (i < 262144) v = s1[i - 196608];
  else if (i < 524288) v = s2[i - 262144];
  else v = s3[i - 524288];
  dst[i] = f2bf(v);
}

// ---------------------------------------------------------------- MFMA GEMM
// Out[n][j] = sum_k A[n][k]*W[j][k] + bias[j] (+ epilogue). BK=64.
// EPI 0: cols<256 *= ATT_SCALE; bf16 out (qkv)
// EPI 1: + extra[n][j]; fp32 out (proj+skip, fc2+skip)
// EPI 2: exact gelu; bf16 out (fc1)
// 128x128 tile, 4 waves -> 64x64 quadrants, 4x4 16x16x32 MFMAs x 2 k-halves.
// LDS: row-major 128x64 bf16, 16B chunk (r,kc) stored at kc_lds = kc^(r&7)
// => fragment ds_read_b128 is 2-way bank aliased (free), staging stride-1.
template <int EPI>
__global__ __launch_bounds__(256, 2) void mfma_gemm(
    const ushort_t* __restrict__ A, const ushort_t* __restrict__ W,
    const float* __restrict__ bias, const float* __restrict__ extra,
    void* __restrict__ OutV, int Kdim, int Jdim)
{
  __shared__ __align__(16) ushort_t As[128 * 64];
  __shared__ __align__(16) ushort_t Bs[128 * 64];
  const int t = threadIdx.x;
  const int lane = t & 63;
  const int w = t >> 6;
  const int wm = w & 1;
  const int wn = w >> 1;
  const int rowbase = blockIdx.y * 128;
  const int colbase = blockIdx.x * 128;

  floatx4 acc[4][4] = {};

  // staging: 4 issues x (A,B); chunk cidx = issue*256 + w*64 + lane,
  // row = cidx>>3, lds k-chunk = cidx&7, global k-chunk = (cidx&7)^(row&7)
  int rA[4], kcg[4];
#pragma unroll
  for (int h = 0; h < 4; ++h) {
    const int cidx = h * 256 + w * 64 + lane;
    const int r = cidx >> 3;
    rA[h] = r;
    kcg[h] = (cidx & 7) ^ (r & 7);
  }

  const int rl = lane & 15;
  const int qd = lane >> 4;  // 0..3

  for (int k0 = 0; k0 < Kdim; k0 += 64) {
#pragma unroll
    for (int h = 0; h < 4; ++h) {
      const int r = rA[h];
      int grow = rowbase + r;
      if (grow > N_NODES - 1) grow = N_NODES - 1;  // clamp tail rows
      const int gcol = colbase + r;                // Jdim multiple of 128
      ushort_t* lbase_a = As + (size_t)(h * 256 + w * 64) * 8;
      ushort_t* lbase_b = Bs + (size_t)(h * 256 + w * 64) * 8;
      gload16(A + (size_t)grow * Kdim + k0 + kcg[h] * 8, lbase_a);
      gload16(W + (size_t)gcol * Kdim + k0 + kcg[h] * 8, lbase_b);
    }
    __syncthreads();

#pragma unroll
    for (int h = 0; h < 2; ++h) {
      short8 af[4], bf[4];
#pragma unroll
      for (int tm = 0; tm < 4; ++tm) {
        const int ra = wm * 64 + tm * 16 + rl;
        const int kc = (h * 4 + qd) ^ (ra & 7);
        af[tm] = *(const short8*)(As + ra * 64 + kc * 8);
      }
#pragma unroll
      for (int tn = 0; tn < 4; ++tn) {
        const int rb = wn * 64 + tn * 16 + rl;
        const int kc = (h * 4 + qd) ^ (rb & 7);
        bf[tn] = *(const short8*)(Bs + rb * 64 + kc * 8);
      }
#pragma unroll
      for (int tm = 0; tm < 4; ++tm)
#pragma unroll
        for (int tn = 0; tn < 4; ++tn)
          acc[tm][tn] = __builtin_amdgcn_mfma_f32_16x16x32_bf16(
              af[tm], bf[tn], acc[tm][tn], 0, 0, 0);
    }
    __syncthreads();
  }

  // Epilogue. C/D layout: col = lane&15, row = (lane>>4)*4 + reg.
#pragma unroll
  for (int tn = 0; tn < 4; ++tn) {
    const int col = colbase + wn * 64 + tn * 16 + rl;
    const float bv = bias[col];
#pragma unroll
    for (int tm = 0; tm < 4; ++tm) {
      const int row0 = rowbase + wm * 64 + tm * 16 + qd * 4;
#pragma unroll
      for (int r = 0; r < 4; ++r) {
        const int row = row0 + r;
        if (row >= N_NODES) continue;
        float v = acc[tm][tn][r] + bv;
        if (EPI == 0) {
          if (col < 256) v *= ATT_SCALE;
          ((ushort_t*)OutV)[(size_t)row * Jdim + col] = f2bf(v);
        } else if (EPI == 1) {
          v += extra[(size_t)row * Jdim + col];
          ((float*)OutV)[(size_t)row * Jdim + col] = v;
        } else {
          v = 0.5f * v * (1.0f + erff(v * 0.70710678118654752f));
          ((ushort_t*)OutV)[(size_t)row * Jdim + col] = f2bf(v);
        }
      }
    }
  }
}

// ---------------------------------------------------------------- edge bucket
__global__ void hist_kernel(const int* __restrict__ idx0, int* __restrict__ counts)
{
  const int m = blockIdx.x * 256 + threadIdx.x;
  if (m < M_EDGES) atomicAdd(&counts[idx0[m]], 1);
}

// parallel scan: (1) per-block exclusive scan + block sums
__global__ __launch_bounds__(256) void scan1_kernel(const int* __restrict__ counts,
    int* __restrict__ offsets, int* __restrict__ bsums)
{
  __shared__ int tmp[256];
  const int t = threadIdx.x;
  const int i = blockIdx.x * 256 + t;
  const int v = (i < N_NODES) ? counts[i] : 0;
  int x = v;
  tmp[t] = x;
  __syncthreads();
#pragma unroll
  for (int off = 1; off < 256; off <<= 1) {
    const int a = (t >= off) ? tmp[t - off] : 0;
    __syncthreads();
    x += a;
    tmp[t] = x;
    __syncthreads();
  }
  if (i < N_NODES) offsets[i] = x - v;
  if (t == 255) bsums[blockIdx.x] = x;
}

// (2) single-block exclusive scan of 196 block sums
__global__ __launch_bounds__(256) void scan2_kernel(int* __restrict__ bsums, int nb)
{
  __shared__ int tmp[256];
  const int t = threadIdx.x;
  const int v = (t < nb) ? bsums[t] : 0;
  int x = v;
  tmp[t] = x;
  __syncthreads();
#pragma unroll
  for (int off = 1; off < 256; off <<= 1) {
    const int a = (t >= off) ? tmp[t - off] : 0;
    __syncthreads();
    x += a;
    tmp[t] = x;
    __syncthreads();
  }
  if (t < nb) bsums[t] = x - v;
}

// (3) add block offsets
__global__ void scan3_kernel(int* __restrict__ offsets, const int* __restrict__ bsums)
{
  const int i = blockIdx.x * 256 + threadIdx.x;
  if (i < N_NODES) offsets[i] += bsums[blockIdx.x];
  if (i == 0) offsets[N_NODES] = M_EDGES;
}

__global__ void scatter_kernel(const int* __restrict__ idx0,
    const int* __restrict__ idx1, const int* __restrict__ offsets,
    int* __restrict__ cursor, int* __restrict__ srcs)
{
  const int m = blockIdx.x * 256 + threadIdx.x;
  if (m < M_EDGES) {
    const int n = idx0[m];
    const int p = offsets[n] + atomicAdd(&cursor[n], 1);
    srcs[p] = idx1[m];
  }
}

// ---------------------------------------------------------------- attention
// One wave per node; lane = slot(0..7) x head(0..7). One-pass online softmax
// in exp2 domain; finite -3e38 sentinel keeps empty lanes NaN-free.
__global__ __launch_bounds__(256) void attn_kernel(
    const ushort_t* __restrict__ QKVh, const int* __restrict__ offsets,
    const int* __restrict__ srcs, ushort_t* __restrict__ AO)
{
  const int node = blockIdx.x * 4 + (threadIdx.x >> 6);
  if (node >= N_NODES) return;
  const int lane = threadIdx.x & 63;
  const int h = lane & 7;
  const int slot = lane >> 3;
  const int start = offsets[node];
  const int end = offsets[node + 1];

  float q[32];
  {
    const uint4* qr = (const uint4*)(QKVh + (size_t)node * 768 + h * 32);
#pragma unroll
    for (int i = 0; i < 4; ++i) {
      const uint4 u = qr[i];
      q[i * 8 + 0] = bf_even(u.x); q[i * 8 + 1] = bf_odd(u.x);
      q[i * 8 + 2] = bf_even(u.y); q[i * 8 + 3] = bf_odd(u.y);
      q[i * 8 + 4] = bf_even(u.z); q[i * 8 + 5] = bf_odd(u.z);
      q[i * 8 + 6] = bf_even(u.w); q[i * 8 + 7] = bf_odd(u.w);
    }
  }

  float m = NEG_BIG, s = 0.f;
  float o[32];
#pragma unroll
  for (int d = 0; d < 32; ++d) o[d] = 0.f;

  for (int e = start + slot; e < end; e += 8) {
    const int sidx = srcs[e];
    const uint4* kr = (const uint4*)(QKVh + (size_t)sidx * 768 + 256 + h * 32);
    float d = 0.f;
#pragma unroll
    for (int i = 0; i < 4; ++i) {
      const uint4 u = kr[i];
      d += q[i * 8 + 0] * bf_even(u.x) + q[i * 8 + 1] * bf_odd(u.x);
      d += q[i * 8 + 2] * bf_even(u.y) + q[i * 8 + 3] * bf_odd(u.y);
      d += q[i * 8 + 4] * bf_even(u.z) + q[i * 8 + 5] * bf_odd(u.z);
      d += q[i * 8 + 6] * bf_even(u.w) + q[i * 8 + 7] * bf_odd(u.w);
    }
    const float l = d * LOG2E;
    const float mn = fmaxf(m, l);
    const float fac = exp2f(m - mn);
    const float wgt = exp2f(l - mn);
    m = mn;
    s = s * fac + wgt;
    const uint4* vr = (const uint4*)(QKVh + (size_t)sidx * 768 + 512 + h * 32);
#pragma unroll
    for (int i = 0; i < 4; ++i) {
      const uint4 u = vr[i];
      o[i * 8 + 0] = o[i * 8 + 0] * fac + wgt * bf_even(u.x);
      o[i * 8 + 1] = o[i * 8 + 1] * fac + wgt * bf_odd(u.x);
      o[i * 8 + 2] = o[i * 8 + 2] * fac + wgt * bf_even(u.y);
      o[i * 8 + 3] = o[i * 8 + 3] * fac + wgt * bf_odd(u.y);
      o[i * 8 + 4] = o[i * 8 + 4] * fac + wgt * bf_even(u.z);
      o[i * 8 + 5] = o[i * 8 + 5] * fac + wgt * bf_odd(u.z);
      o[i * 8 + 6] = o[i * 8 + 6] * fac + wgt * bf_even(u.w);
      o[i * 8 + 7] = o[i * 8 + 7] * fac + wgt * bf_odd(u.w);
    }
  }

  // global max over slots, then rescale local (s,o) and plain-sum reduce
  float mx = m;
  mx = fmaxf(mx, __shfl_xor(mx, 8));
  mx = fmaxf(mx, __shfl_xor(mx, 16));
  mx = fmaxf(mx, __shfl_xor(mx, 32));
  const float fac = exp2f(m - mx);  // finite sentinel: empty lane -> 0 or 1(&s=0)
  s *= fac;
#pragma unroll
  for (int d = 0; d < 32; ++d) o[d] *= fac;

  s += __shfl_xor(s, 8);
  s += __shfl_xor(s, 16);
  s += __shfl_xor(s, 32);

  // reduce-scatter o[32] across 8 slots (static reg indices only)
  {
    const bool up = (slot & 4) != 0;
#pragma unroll
    for (int i = 0; i < 16; ++i) {
      const float send = up ? o[i] : o[i + 16];
      const float recv = __shfl_xor(send, 32);
      o[i] = (up ? o[i + 16] : o[i]) + recv;
    }
  }
  {
    const bool up = (slot & 2) != 0;
#pragma unroll
    for (int i = 0; i < 8; ++i) {
      const float send = up ? o[i] : o[i + 8];
      const float recv = __shfl_xor(send, 16);
      o[i] = (up ? o[i + 8] : o[i]) + recv;
    }
  }
  {
    const bool up = (slot & 1) != 0;
#pragma unroll
    for (int i = 0; i < 4; ++i) {
      const float send = up ? o[i] : o[i + 4];
      const float recv = __shfl_xor(send, 8);
      o[i] = (up ? o[i + 4] : o[i]) + recv;
    }
  }
  const int dbase = ((slot & 4) ? 16 : 0) + ((slot & 2) ? 8 : 0) +
                    ((slot & 1) ? 4 : 0);
  const float inv = (end > start) ? 1.0f / s : 0.0f;
  ushort4 st;
  st.x = f2bf(o[0] * inv); st.y = f2bf(o[1] * inv);
  st.z = f2bf(o[2] * inv); st.w = f2bf(o[3] * inv);
  *(ushort4*)(AO + (size_t)node * 256 + h * 32 + dbase) = st;
}

// ---------------------------------------------------------------- launch
extern "C" void kernel_launch(void* const* d_in, const int* in_sizes, int n_in,
                              void* d_out, int out_size, void* d_ws,
                              size_t ws_size, hipStream_t stream)
{
  const float* feats  = (const float*)d_in[0];
  const int*   edge   = (const int*)d_in[2];
  const float* ln1_g  = (const float*)d_in[3];
  const float* ln1_b  = (const float*)d_in[4];
  const float* qkv_w  = (const float*)d_in[5];
  const float* qkv_b  = (const float*)d_in[6];
  const float* proj_w = (const float*)d_in[7];
  const float* proj_b = (const float*)d_in[8];
  const float* ln2_g  = (const float*)d_in[9];
  const float* ln2_b  = (const float*)d_in[10];
  const float* fc1_w  = (const float*)d_in[11];
  const float* fc1_b  = (const float*)d_in[12];
  const float* fc2_w  = (const float*)d_in[13];
  const float* fc2_b  = (const float*)d_in[14];
  float* out = (float*)d_out;

  // ws layout (QKVh+AOb contiguous -> reused as H bf16 N*1024)
  ushort_t* Xb   = (ushort_t*)d_ws;                       // N*256 bf16
  ushort_t* QKVh = Xb + (size_t)N_NODES * 256;            // N*768 bf16
  ushort_t* AOb  = QKVh + (size_t)N_NODES * 768;          // N*256 bf16
  ushort_t* Hb   = QKVh;                                  // N*1024 overlay
  ushort_t* wb   = AOb + (size_t)N_NODES * 256;           // 786432 bf16
  ushort_t* qkv_wb  = wb;
  ushort_t* proj_wb = qkv_wb + 768 * 256;
  ushort_t* fc1_wb  = proj_wb + 256 * 256;
  ushort_t* fc2_wb  = fc1_wb + 1024 * 256;
  int* counts  = (int*)(fc2_wb + 256 * 1024);
  int* cursor  = counts + N_NODES;
  int* offsets = cursor + N_NODES;
  int* srcs    = offsets + N_NODES + 1;
  int* bsums   = srcs + M_EDGES;
  const size_t required = (size_t)((char*)(bsums + 256) - (char*)d_ws);
  if (ws_size < required) {  // diagnostic fallback: fail absmax, don't fault
    hipMemsetAsync(d_out, 0, (size_t)out_size * sizeof(float), stream);
    return;
  }
  const int* idx0 = edge;
  const int* idx1 = edge + M_EDGES;
  const int rowTiles = (N_NODES + 127) / 128;  // 391
  const int scanBlocks = (N_NODES + 255) / 256;  // 196

  hipMemsetAsync(counts, 0, 2 * N_NODES * sizeof(int), stream);
  cvt_kernel<<<786432 / 256, 256, 0, stream>>>(qkv_w, proj_w, fc1_w, fc2_w, wb);

  ln_kernel<<<N_NODES, 256, 0, stream>>>(feats, ln1_g, ln1_b, Xb);
  mfma_gemm<0><<<dim3(768 / 128, rowTiles), 256, 0, stream>>>(
      Xb, qkv_wb, qkv_b, nullptr, QKVh, 256, 768);
  hist_kernel<<<(M_EDGES + 255) / 256, 256, 0, stream>>>(idx0, counts);
  scan1_kernel<<<scanBlocks, 256, 0, stream>>>(counts, offsets, bsums);
  scan2_kernel<<<1, 256, 0, stream>>>(bsums, scanBlocks);
  scan3_kernel<<<scanBlocks, 256, 0, stream>>>(offsets, bsums);
  scatter_kernel<<<(M_EDGES + 255) / 256, 256, 0, stream>>>(idx0, idx1, offsets,
                                                            cursor, srcs);
  attn_kernel<<<N_NODES / 4, 256, 0, stream>>>(QKVh, offsets, srcs, AOb);
  mfma_gemm<1><<<dim3(256 / 128, rowTiles), 256, 0, stream>>>(
      AOb, proj_wb, proj_b, feats, out, 256, 256);
  ln_kernel<<<N_NODES, 256, 0, stream>>>(out, ln2_g, ln2_b, Xb);
  mfma_gemm<2><<<dim3(1024 / 128, rowTiles), 256, 0, stream>>>(
      Xb, fc1_wb, fc1_b, nullptr, Hb, 256, 1024);
  mfma_gemm<1><<<dim3(256 / 128, rowTiles), 256, 0, stream>>>(
      Hb, fc2_wb, fc2_b, out, out, 1024, 256);
}

// Round 5
// 564.535 us; speedup vs baseline: 3.0010x; 1.1604x over previous
//
#include <hip/hip_runtime.h>
#include <hip/hip_bf16.h>
#include <cmath>

// TransformerBlock: N=50000, C=256, H=8, HD=32, M=800000 edges, HID=1024.
// Round 5: LDS-staged GEMM epilogue -> full-cache-line vector stores
// (round-4 fc2 showed WRITE 210MB vs 51MB ideal, 2.6TB/s: scalar stores of
// MFMA column fragments = partial-line writes). bias/extra reads vectorized;
// gelu switched to tanh form (exact erf ~25 VALU x 51M elems).
// ws: Xb 25.6MB | QKVh 76.8MB | AOb 25.6MB (QKVh+AOb reused as H 102.4MB)
//     | wb 1.6MB | int meta ~3.8MB => ~133.5MB.

#define N_NODES 50000
#define C_DIM 256
#define M_EDGES 800000
#define ATT_SCALE 0.17677669529663687f /* 32^-0.5 */
#define LN_EPS 1e-5f
#define LOG2E 1.4426950408889634f
#define NEG_BIG -3.0e38f

typedef unsigned int uint_t;
typedef unsigned short ushort_t;
typedef short short8 __attribute__((ext_vector_type(8)));
typedef float floatx4 __attribute__((ext_vector_type(4)));

__device__ __forceinline__ ushort_t f2bf(float f) {
  uint_t u = __float_as_uint(f);
  return (ushort_t)((u + 0x7FFFu + ((u >> 16) & 1u)) >> 16);  // RNE
}
__device__ __forceinline__ float bf_even(uint_t u) { return __uint_as_float(u << 16); }
__device__ __forceinline__ float bf_odd(uint_t u) { return __uint_as_float(u & 0xFFFF0000u); }

__device__ __forceinline__ float gelu_tanh(float x) {
  // tanh-form gelu; |diff vs exact erf gelu| <= ~3e-3, within error budget
  const float u = 0.7978845608028654f * (x + 0.044715f * x * x * x);
  const float e = __expf(2.0f * u);
  const float t = 1.0f - 2.0f / (e + 1.0f);
  return 0.5f * x * (1.0f + t);
}

__device__ __forceinline__ void gload16(const void* g, void* l) {
  __builtin_amdgcn_global_load_lds(
      (const __attribute__((address_space(1))) void*)g,
      (__attribute__((address_space(3))) void*)l, 16, 0, 0);
}

// ---------------------------------------------------------------- LayerNorm
__global__ __launch_bounds__(256) void ln_kernel(const float* __restrict__ x,
    const float* __restrict__ g, const float* __restrict__ b,
    ushort_t* __restrict__ y)
{
  __shared__ float red[8];
  const int n = blockIdx.x;
  const int t = threadIdx.x;
  float v = x[(size_t)n * C_DIM + t];
  float s = v, s2 = v * v;
#pragma unroll
  for (int m = 1; m < 64; m <<= 1) {
    s += __shfl_xor(s, m);
    s2 += __shfl_xor(s2, m);
  }
  const int wave = t >> 6;
  if ((t & 63) == 0) { red[wave] = s; red[4 + wave] = s2; }
  __syncthreads();
  s = red[0] + red[1] + red[2] + red[3];
  s2 = red[4] + red[5] + red[6] + red[7];
  const float mean = s * (1.0f / 256.0f);
  const float var = fmaxf(s2 * (1.0f / 256.0f) - mean * mean, 0.0f);
  const float r = rsqrtf(var + LN_EPS);
  y[(size_t)n * C_DIM + t] = f2bf((v - mean) * r * g[t] + b[t]);
}

// ------------------------------------------------- fused fp32->bf16 weights
__global__ void cvt_kernel(const float* __restrict__ s0, const float* __restrict__ s1,
                           const float* __restrict__ s2, const float* __restrict__ s3,
                           ushort_t* __restrict__ dst)
{
  const int i = blockIdx.x * 256 + threadIdx.x;
  // segments: qkv_w 196608 | proj_w 65536 | fc1_w 262144 | fc2_w 262144
  float v;
  if (i < 196608) v = s0[i];
  else if (i < 262144) v = s1[i - 196608];
  else if (i < 524288) v = s2[i - 262144];
  else v = s3[i - 524288];
  dst[i] = f2bf(v);
}

// ---------------------------------------------------------------- MFMA GEMM
// Out[n][j] = sum_k A[n][k]*W[j][k] + bias[j] (+ epilogue). BK=64.
// EPI 0: cols<256 *= ATT_SCALE; bf16 out (qkv)
// EPI 1: + extra[n][j]; fp32 out (proj+skip, fc2+skip)
// EPI 2: tanh-gelu; bf16 out (fc1)
// 128x128 tile, 4 waves -> 64x64 quadrants, 4x4 16x16x32 MFMAs x 2 k-halves.
// K-loop LDS: row-major 128x64 bf16, chunk (r,kc) at kc_lds=kc^(r&7).
// Epilogue: per-wave LDS transpose (9216B/wave) -> float4/ushort8 stores,
// full 128B lines (fixes round-4's 4x write amplification).
template <int EPI>
__global__ __launch_bounds__(256, 2) void mfma_gemm(
    const ushort_t* __restrict__ A, const ushort_t* __restrict__ W,
    const float* __restrict__ bias, const float* __restrict__ extra,
    void* __restrict__ OutV, int Kdim, int Jdim)
{
  __shared__ __align__(16) char smem[36864];  // 32KB staging / 36KB epilogue
  ushort_t* As = (ushort_t*)smem;
  ushort_t* Bs = As + 128 * 64;
  const int t = threadIdx.x;
  const int lane = t & 63;
  const int w = t >> 6;
  const int wm = w & 1;
  const int wn = w >> 1;
  const int rowbase = blockIdx.y * 128;
  const int colbase = blockIdx.x * 128;

  floatx4 acc[4][4] = {};

  int rA[4], kcg[4];
#pragma unroll
  for (int h = 0; h < 4; ++h) {
    const int cidx = h * 256 + w * 64 + lane;
    const int r = cidx >> 3;
    rA[h] = r;
    kcg[h] = (cidx & 7) ^ (r & 7);
  }

  const int rl = lane & 15;
  const int qd = lane >> 4;  // 0..3

  for (int k0 = 0; k0 < Kdim; k0 += 64) {
#pragma unroll
    for (int h = 0; h < 4; ++h) {
      const int r = rA[h];
      int grow = rowbase + r;
      if (grow > N_NODES - 1) grow = N_NODES - 1;  // clamp tail rows
      const int gcol = colbase + r;                // Jdim multiple of 128
      ushort_t* lbase_a = As + (size_t)(h * 256 + w * 64) * 8;
      ushort_t* lbase_b = Bs + (size_t)(h * 256 + w * 64) * 8;
      gload16(A + (size_t)grow * Kdim + k0 + kcg[h] * 8, lbase_a);
      gload16(W + (size_t)gcol * Kdim + k0 + kcg[h] * 8, lbase_b);
    }
    __syncthreads();

#pragma unroll
    for (int h = 0; h < 2; ++h) {
      short8 af[4], bf[4];
#pragma unroll
      for (int tm = 0; tm < 4; ++tm) {
        const int ra = wm * 64 + tm * 16 + rl;
        const int kc = (h * 4 + qd) ^ (ra & 7);
        af[tm] = *(const short8*)(As + ra * 64 + kc * 8);
      }
#pragma unroll
      for (int tn = 0; tn < 4; ++tn) {
        const int rb = wn * 64 + tn * 16 + rl;
        const int kc = (h * 4 + qd) ^ (rb & 7);
        bf[tn] = *(const short8*)(Bs + rb * 64 + kc * 8);
      }
#pragma unroll
      for (int tm = 0; tm < 4; ++tm)
#pragma unroll
        for (int tn = 0; tn < 4; ++tn)
          acc[tm][tn] = __builtin_amdgcn_mfma_f32_16x16x32_bf16(
              af[tm], bf[tn], acc[tm][tn], 0, 0, 0);
    }
    __syncthreads();
  }

  // ---- epilogue: LDS transpose -> full-line vector stores ----
  const int q8 = lane >> 3;  // 0..7 (row-group in read phase)
  const int c8 = lane & 7;   // 0..7 (col quad/oct in read phase)
  if (EPI == 1) {
    float* sc = (float*)smem + w * (64 * 36);  // 64 rows x stride 36 fp32
#pragma unroll
    for (int p = 0; p < 2; ++p) {
      __syncthreads();
#pragma unroll
      for (int th = 0; th < 2; ++th) {
        const int tn = p * 2 + th;
#pragma unroll
        for (int tm = 0; tm < 4; ++tm)
#pragma unroll
          for (int r = 0; r < 4; ++r)
            sc[(tm * 16 + qd * 4 + r) * 36 + th * 16 + rl] = acc[tm][tn][r];
      }
      __syncthreads();
      const int col0 = colbase + wn * 64 + p * 32 + c8 * 4;
      const float4 b4 = *(const float4*)(bias + col0);
#pragma unroll
      for (int it = 0; it < 8; ++it) {
        const int lr = it * 8 + q8;
        const int grow = rowbase + wm * 64 + lr;
        if (grow >= N_NODES) continue;
        float4 v = *(const float4*)(sc + lr * 36 + c8 * 4);
        const float4 e4 = *(const float4*)(extra + (size_t)grow * Jdim + col0);
        v.x += b4.x + e4.x; v.y += b4.y + e4.y;
        v.z += b4.z + e4.z; v.w += b4.w + e4.w;
        *(float4*)((float*)OutV + (size_t)grow * Jdim + col0) = v;
      }
    }
  } else {
    ushort_t* su = (ushort_t*)smem + w * (64 * 72);  // 64 rows x stride 72
#pragma unroll
    for (int tn = 0; tn < 4; ++tn) {
      const int col = colbase + wn * 64 + tn * 16 + rl;
      const float bv = bias[col];
#pragma unroll
      for (int tm = 0; tm < 4; ++tm)
#pragma unroll
        for (int r = 0; r < 4; ++r) {
          float v = acc[tm][tn][r] + bv;
          if (EPI == 0) {
            if (col < 256) v *= ATT_SCALE;
          } else {
            v = gelu_tanh(v);
          }
          su[(tm * 16 + qd * 4 + r) * 72 + tn * 16 + rl] = f2bf(v);
        }
    }
    __syncthreads();
#pragma unroll
    for (int it = 0; it < 8; ++it) {
      const int lr = it * 8 + q8;
      const int grow = rowbase + wm * 64 + lr;
      if (grow >= N_NODES) continue;
      const uint4 v = *(const uint4*)(su + lr * 72 + c8 * 8);
      *(uint4*)((ushort_t*)OutV + (size_t)grow * Jdim + colbase + wn * 64 + c8 * 8) = v;
    }
  }
}

// ---------------------------------------------------------------- edge bucket
__global__ void hist_kernel(const int* __restrict__ idx0, int* __restrict__ counts)
{
  const int m = blockIdx.x * 256 + threadIdx.x;
  if (m < M_EDGES) atomicAdd(&counts[idx0[m]], 1);
}

__global__ __launch_bounds__(256) void scan1_kernel(const int* __restrict__ counts,
    int* __restrict__ offsets, int* __restrict__ bsums)
{
  __shared__ int tmp[256];
  const int t = threadIdx.x;
  const int i = blockIdx.x * 256 + t;
  const int v = (i < N_NODES) ? counts[i] : 0;
  int x = v;
  tmp[t] = x;
  __syncthreads();
#pragma unroll
  for (int off = 1; off < 256; off <<= 1) {
    const int a = (t >= off) ? tmp[t - off] : 0;
    __syncthreads();
    x += a;
    tmp[t] = x;
    __syncthreads();
  }
  if (i < N_NODES) offsets[i] = x - v;
  if (t == 255) bsums[blockIdx.x] = x;
}

__global__ __launch_bounds__(256) void scan2_kernel(int* __restrict__ bsums, int nb)
{
  __shared__ int tmp[256];
  const int t = threadIdx.x;
  const int v = (t < nb) ? bsums[t] : 0;
  int x = v;
  tmp[t] = x;
  __syncthreads();
#pragma unroll
  for (int off = 1; off < 256; off <<= 1) {
    const int a = (t >= off) ? tmp[t - off] : 0;
    __syncthreads();
    x += a;
    tmp[t] = x;
    __syncthreads();
  }
  if (t < nb) bsums[t] = x - v;
}

__global__ void scan3_kernel(int* __restrict__ offsets, const int* __restrict__ bsums)
{
  const int i = blockIdx.x * 256 + threadIdx.x;
  if (i < N_NODES) offsets[i] += bsums[blockIdx.x];
  if (i == 0) offsets[N_NODES] = M_EDGES;
}

__global__ void scatter_kernel(const int* __restrict__ idx0,
    const int* __restrict__ idx1, const int* __restrict__ offsets,
    int* __restrict__ cursor, int* __restrict__ srcs)
{
  const int m = blockIdx.x * 256 + threadIdx.x;
  if (m < M_EDGES) {
    const int n = idx0[m];
    const int p = offsets[n] + atomicAdd(&cursor[n], 1);
    srcs[p] = idx1[m];
  }
}

// ---------------------------------------------------------------- attention
__global__ __launch_bounds__(256) void attn_kernel(
    const ushort_t* __restrict__ QKVh, const int* __restrict__ offsets,
    const int* __restrict__ srcs, ushort_t* __restrict__ AO)
{
  const int node = blockIdx.x * 4 + (threadIdx.x >> 6);
  if (node >= N_NODES) return;
  const int lane = threadIdx.x & 63;
  const int h = lane & 7;
  const int slot = lane >> 3;
  const int start = offsets[node];
  const int end = offsets[node + 1];

  float q[32];
  {
    const uint4* qr = (const uint4*)(QKVh + (size_t)node * 768 + h * 32);
#pragma unroll
    for (int i = 0; i < 4; ++i) {
      const uint4 u = qr[i];
      q[i * 8 + 0] = bf_even(u.x); q[i * 8 + 1] = bf_odd(u.x);
      q[i * 8 + 2] = bf_even(u.y); q[i * 8 + 3] = bf_odd(u.y);
      q[i * 8 + 4] = bf_even(u.z); q[i * 8 + 5] = bf_odd(u.z);
      q[i * 8 + 6] = bf_even(u.w); q[i * 8 + 7] = bf_odd(u.w);
    }
  }

  float m = NEG_BIG, s = 0.f;
  float o[32];
#pragma unroll
  for (int d = 0; d < 32; ++d) o[d] = 0.f;

  for (int e = start + slot; e < end; e += 8) {
    const int sidx = srcs[e];
    const uint4* kr = (const uint4*)(QKVh + (size_t)sidx * 768 + 256 + h * 32);
    float d = 0.f;
#pragma unroll
    for (int i = 0; i < 4; ++i) {
      const uint4 u = kr[i];
      d += q[i * 8 + 0] * bf_even(u.x) + q[i * 8 + 1] * bf_odd(u.x);
      d += q[i * 8 + 2] * bf_even(u.y) + q[i * 8 + 3] * bf_odd(u.y);
      d += q[i * 8 + 4] * bf_even(u.z) + q[i * 8 + 5] * bf_odd(u.z);
      d += q[i * 8 + 6] * bf_even(u.w) + q[i * 8 + 7] * bf_odd(u.w);
    }
    const float l = d * LOG2E;
    const float mn = fmaxf(m, l);
    const float fac = exp2f(m - mn);
    const float wgt = exp2f(l - mn);
    m = mn;
    s = s * fac + wgt;
    const uint4* vr = (const uint4*)(QKVh + (size_t)sidx * 768 + 512 + h * 32);
#pragma unroll
    for (int i = 0; i < 4; ++i) {
      const uint4 u = vr[i];
      o[i * 8 + 0] = o[i * 8 + 0] * fac + wgt * bf_even(u.x);
      o[i * 8 + 1] = o[i * 8 + 1] * fac + wgt * bf_odd(u.x);
      o[i * 8 + 2] = o[i * 8 + 2] * fac + wgt * bf_even(u.y);
      o[i * 8 + 3] = o[i * 8 + 3] * fac + wgt * bf_odd(u.y);
      o[i * 8 + 4] = o[i * 8 + 4] * fac + wgt * bf_even(u.z);
      o[i * 8 + 5] = o[i * 8 + 5] * fac + wgt * bf_odd(u.z);
      o[i * 8 + 6] = o[i * 8 + 6] * fac + wgt * bf_even(u.w);
      o[i * 8 + 7] = o[i * 8 + 7] * fac + wgt * bf_odd(u.w);
    }
  }

  float mx = m;
  mx = fmaxf(mx, __shfl_xor(mx, 8));
  mx = fmaxf(mx, __shfl_xor(mx, 16));
  mx = fmaxf(mx, __shfl_xor(mx, 32));
  const float fac = exp2f(m - mx);
  s *= fac;
#pragma unroll
  for (int d = 0; d < 32; ++d) o[d] *= fac;

  s += __shfl_xor(s, 8);
  s += __shfl_xor(s, 16);
  s += __shfl_xor(s, 32);

  {
    const bool up = (slot & 4) != 0;
#pragma unroll
    for (int i = 0; i < 16; ++i) {
      const float send = up ? o[i] : o[i + 16];
      const float recv = __shfl_xor(send, 32);
      o[i] = (up ? o[i + 16] : o[i]) + recv;
    }
  }
  {
    const bool up = (slot & 2) != 0;
#pragma unroll
    for (int i = 0; i < 8; ++i) {
      const float send = up ? o[i] : o[i + 8];
      const float recv = __shfl_xor(send, 16);
      o[i] = (up ? o[i + 8] : o[i]) + recv;
    }
  }
  {
    const bool up = (slot & 1) != 0;
#pragma unroll
    for (int i = 0; i < 4; ++i) {
      const float send = up ? o[i] : o[i + 4];
      const float recv = __shfl_xor(send, 8);
      o[i] = (up ? o[i + 4] : o[i]) + recv;
    }
  }
  const int dbase = ((slot & 4) ? 16 : 0) + ((slot & 2) ? 8 : 0) +
                    ((slot & 1) ? 4 : 0);
  const float inv = (end > start) ? 1.0f / s : 0.0f;
  ushort4 st;
  st.x = f2bf(o[0] * inv); st.y = f2bf(o[1] * inv);
  st.z = f2bf(o[2] * inv); st.w = f2bf(o[3] * inv);
  *(ushort4*)(AO + (size_t)node * 256 + h * 32 + dbase) = st;
}

// ---------------------------------------------------------------- launch
extern "C" void kernel_launch(void* const* d_in, const int* in_sizes, int n_in,
                              void* d_out, int out_size, void* d_ws,
                              size_t ws_size, hipStream_t stream)
{
  const float* feats  = (const float*)d_in[0];
  const int*   edge   = (const int*)d_in[2];
  const float* ln1_g  = (const float*)d_in[3];
  const float* ln1_b  = (const float*)d_in[4];
  const float* qkv_w  = (const float*)d_in[5];
  const float* qkv_b  = (const float*)d_in[6];
  const float* proj_w = (const float*)d_in[7];
  const float* proj_b = (const float*)d_in[8];
  const float* ln2_g  = (const float*)d_in[9];
  const float* ln2_b  = (const float*)d_in[10];
  const float* fc1_w  = (const float*)d_in[11];
  const float* fc1_b  = (const float*)d_in[12];
  const float* fc2_w  = (const float*)d_in[13];
  const float* fc2_b  = (const float*)d_in[14];
  float* out = (float*)d_out;

  ushort_t* Xb   = (ushort_t*)d_ws;                       // N*256 bf16
  ushort_t* QKVh = Xb + (size_t)N_NODES * 256;            // N*768 bf16
  ushort_t* AOb  = QKVh + (size_t)N_NODES * 768;          // N*256 bf16
  ushort_t* Hb   = QKVh;                                  // N*1024 overlay
  ushort_t* wb   = AOb + (size_t)N_NODES * 256;           // 786432 bf16
  ushort_t* qkv_wb  = wb;
  ushort_t* proj_wb = qkv_wb + 768 * 256;
  ushort_t* fc1_wb  = proj_wb + 256 * 256;
  ushort_t* fc2_wb  = fc1_wb + 1024 * 256;
  int* counts  = (int*)(fc2_wb + 256 * 1024);
  int* cursor  = counts + N_NODES;
  int* offsets = cursor + N_NODES;
  int* srcs    = offsets + N_NODES + 1;
  int* bsums   = srcs + M_EDGES;
  const size_t required = (size_t)((char*)(bsums + 256) - (char*)d_ws);
  if (ws_size < required) {
    hipMemsetAsync(d_out, 0, (size_t)out_size * sizeof(float), stream);
    return;
  }
  const int* idx0 = edge;
  const int* idx1 = edge + M_EDGES;
  const int rowTiles = (N_NODES + 127) / 128;    // 391
  const int scanBlocks = (N_NODES + 255) / 256;  // 196

  hipMemsetAsync(counts, 0, 2 * N_NODES * sizeof(int), stream);
  cvt_kernel<<<786432 / 256, 256, 0, stream>>>(qkv_w, proj_w, fc1_w, fc2_w, wb);

  ln_kernel<<<N_NODES, 256, 0, stream>>>(feats, ln1_g, ln1_b, Xb);
  mfma_gemm<0><<<dim3(768 / 128, rowTiles), 256, 0, stream>>>(
      Xb, qkv_wb, qkv_b, nullptr, QKVh, 256, 768);
  hist_kernel<<<(M_EDGES + 255) / 256, 256, 0, stream>>>(idx0, counts);
  scan1_kernel<<<scanBlocks, 256, 0, stream>>>(counts, offsets, bsums);
  scan2_kernel<<<1, 256, 0, stream>>>(bsums, scanBlocks);
  scan3_kernel<<<scanBlocks, 256, 0, stream>>>(offsets, bsums);
  scatter_kernel<<<(M_EDGES + 255) / 256, 256, 0, stream>>>(idx0, idx1, offsets,
                                                            cursor, srcs);
  attn_kernel<<<N_NODES / 4, 256, 0, stream>>>(QKVh, offsets, srcs, AOb);
  mfma_gemm<1><<<dim3(256 / 128, rowTiles), 256, 0, stream>>>(
      AOb, proj_wb, proj_b, feats, out, 256, 256);
  ln_kernel<<<N_NODES, 256, 0, stream>>>(out, ln2_g, ln2_b, Xb);
  mfma_gemm<2><<<dim3(1024 / 128, rowTiles), 256, 0, stream>>>(
      Xb, fc1_wb, fc1_b, nullptr, Hb, 256, 1024);
  mfma_gemm<1><<<dim3(256 / 128, rowTiles), 256, 0, stream>>>(
      Hb, fc2_wb, fc2_b, out, out, 1024, 256);
}